// Round 16
// baseline (193.388 us; speedup 1.0000x reference)
//
#include <hip/hip_runtime.h>
#include <hip/hip_cooperative_groups.h>
#include <stdint.h>
#include <math.h>

namespace cg = cooperative_groups;

// ----------------------------------------------------------------------------
// SparseKVCache: keep top-k by |x| (k = n/2), zero the rest. Exact.
// R16 = R15 with the two refine kernels MERGED into one cooperative kernel:
//   zero_ws -> sample_bracket -> fused_main -> refine (cooperative):
//     A: candidate hist  -> grid.sync
//     B: redundant per-block sub-bin select (base2/rem2 in registers)
//     C: own-segment fixup (restore definite keeps, compact in-sub-bin)
//        -> grid.sync
//     D: block 0 exact stable rank over compact set (ties: smallest index)
// No same-address global atomics in hot paths. Deterministic.
// ----------------------------------------------------------------------------

#define NTHR 256
#define MASK31 0x7fffffffu

typedef unsigned int v4u __attribute__((ext_vector_type(4)));

// ---- ws layout (uint32 words) ----
#define SH_OFF    0            // 8192-bin sample histogram (bits 30..18)
#define SH_BINS   8192
#define CH_OFF    8192         // 4096-bin candidate histogram
#define CH_BINS   4096
#define SCL_OFF   12288        // scalars:
//  [0]=uLo [1]=uHi [2]=shift1 [5]=ovfPairCnt [7]=done1 [9]=cmpCnt
#define ZERO_WORDS 12320
#define HIC_OFF   12320        // per-block hi counts (4096)
#define PCN_OFF   16416        // per-block pair counts (4096)
#define OVFP_OFF  20512        // overflow pairs (even => 8B aligned)
#define OVFP_CAP  16384
#define CMP_OFF   53536        // compact in-sub-bin pairs (even => 8B aligned)
#define CMP_CAP   4096
#define PAIRS_OFF 131072       // per-block pair segments: 4096 x 1024 pairs
#define SEG_CAP   1024
#define NBLK_MAIN 4096
#define STG_CAP   1024         // LDS pair stage (8 KB)

__global__ void zero_ws_kernel(uint32_t* __restrict__ ws) {
    int i = blockIdx.x * blockDim.x + threadIdx.x;
    if (i < ZERO_WORDS) ws[i] = 0;
}

// ---- sample hist (1/32 of data, 8KB runs) + last-block bracket select ------
__global__ void sample_bracket_kernel(const v4u* __restrict__ xv, long long n4,
                                      uint32_t* __restrict__ ws,
                                      uint32_t ksmM, uint32_t kspM) {
    __shared__ uint32_t lh[SH_BINS];
    __shared__ uint32_t csum[NTHR];
    __shared__ uint32_t cpre[NTHR];
    __shared__ int sBHi, sB1, amLast;
    for (int i = threadIdx.x; i < SH_BINS; i += NTHR) lh[i] = 0;
    __syncthreads();
    long long S4 = n4 >> 5;                 // sampled uint4 count (1/32)
    long long T = (long long)gridDim.x * NTHR;
    for (long long s = (long long)blockIdx.x * NTHR + threadIdx.x; s < S4; s += T) {
        long long idx4 = ((s >> 9) << 14) | (s & 511);  // 512-uint4 runs /16384
        if (idx4 < n4) {
            v4u v = xv[idx4];
            atomicAdd(&lh[(v.x & MASK31) >> 18], 1u);
            atomicAdd(&lh[(v.y & MASK31) >> 18], 1u);
            atomicAdd(&lh[(v.z & MASK31) >> 18], 1u);
            atomicAdd(&lh[(v.w & MASK31) >> 18], 1u);
        }
    }
    __syncthreads();
    for (int i = threadIdx.x; i < SH_BINS; i += NTHR)
        if (lh[i]) atomicAdd(&ws[SH_OFF + i], lh[i]);
    __syncthreads();   // drains vmcnt: this block's atomics are device-visible
    if (threadIdx.x == 0) {
        uint32_t old = atomicAdd(&ws[SCL_OFF + 7], 1u);
        amLast = (old == gridDim.x - 1u) ? 1 : 0;
        sBHi = -1; sB1 = -1;
    }
    __syncthreads();
    if (!amLast) return;
    for (int i = threadIdx.x; i < SH_BINS; i += NTHR)
        lh[i] = atomicAdd(&ws[SH_OFF + i], 0u);
    __syncthreads();
    uint32_t s = 0;
    for (int i = 0; i < 32; ++i) s += lh[threadIdx.x * 32 + i];
    csum[threadIdx.x] = s;
    __syncthreads();
    if (threadIdx.x == 0) {
        uint32_t run = 0;
        for (int c = NTHR - 1; c >= 0; --c) { cpre[c] = run; run += csum[c]; }
    }
    __syncthreads();
    {
        int c = threadIdx.x;
        int hitHi = -1, hitB1 = -1;
        uint32_t excl = cpre[c];
        for (int bb = c * 32 + 31; bb >= c * 32; --bb) {
            uint32_t cnt = lh[bb];
            uint32_t incl = excl + cnt;
            if (hitHi < 0 && incl >= ksmM) hitHi = bb;
            if (hitB1 < 0 && excl >= kspM) hitB1 = bb;
            excl = incl;
        }
        if (hitHi >= 0) atomicMax(&sBHi, hitHi);
        if (hitB1 >= 0) atomicMax(&sB1, hitB1);
    }
    __syncthreads();
    if (threadIdx.x == 0) {
        int bHi = sBHi < 0 ? 0 : sBHi;
        int bLo = sB1 + 1;
        if (bLo > bHi) bLo = bHi;
        if (bLo < 0) bLo = 0;
        int sbins = bHi - bLo + 1;
        int clog = 0; while ((1 << clog) < sbins) ++clog;
        int spanBits = 18 + clog;
        int shift1 = spanBits - 12;            // 4096 bins over the span
        if (shift1 < 0) shift1 = 0;
        ws[SCL_OFF + 0] = ((uint32_t)bLo) << 18;          // uLo
        ws[SCL_OFF + 1] = ((uint32_t)(bHi + 1)) << 18;    // uHi (exclusive)
        ws[SCL_OFF + 2] = (uint32_t)shift1;
    }
}

// ---- fused full pass: register candidate capture; overflow rescans self ----
__global__ void fused_main_kernel(const uint32_t* __restrict__ x,
                                  uint32_t* __restrict__ out, long long n,
                                  uint32_t* __restrict__ ws) {
    __shared__ uint2 stage[STG_CAP];     // 8 KB
    __shared__ uint32_t cnt, redHi[NTHR / 64];
    const uint32_t uLo = ws[SCL_OFF + 0];
    const uint32_t uHi = ws[SCL_OFF + 1];
    const uint32_t span = uHi - uLo;
    if (threadIdx.x == 0) cnt = 0u;
    __syncthreads();

    const v4u* __restrict__ xv = (const v4u*)x;
    v4u* __restrict__ ov = (v4u*)out;
    long long n4 = n >> 2;
    const long long stride = (long long)gridDim.x * NTHR;
    const long long i0 = (long long)blockIdx.x * NTHR + threadIdx.x;

    uint32_t myHi = 0;
    uint32_t myCnt = 0;
    uint32_t s0v = 0, s0i = 0, s1v = 0, s1i = 0;
    uint32_t s2v = 0, s2i = 0, s3v = 0, s3i = 0;

    for (long long i = i0; i < n4; i += stride) {
        v4u v = xv[i];
        uint32_t c0 = v.x & MASK31, c1 = v.y & MASK31;
        uint32_t c2 = v.z & MASK31, c3 = v.w & MASK31;
        myHi += (uint32_t)(c0 >= uHi) + (uint32_t)(c1 >= uHi)
              + (uint32_t)(c2 >= uHi) + (uint32_t)(c3 >= uHi);
        v4u o;
        o.x = (c0 >= uHi) ? v.x : 0u;
        o.y = (c1 >= uHi) ? v.y : 0u;
        o.z = (c2 >= uHi) ? v.z : 0u;
        o.w = (c3 >= uHi) ? v.w : 0u;
        uint32_t h0 = (c0 - uLo) < span ? 1u : 0u;
        uint32_t h1 = (c1 - uLo) < span ? 1u : 0u;
        uint32_t h2 = (c2 - uLo) < span ? 1u : 0u;
        uint32_t h3 = (c3 - uLo) < span ? 1u : 0u;
        if (h0 | h1 | h2 | h3) {
            uint32_t e0 = (uint32_t)(i << 2);
#define CAPT(hx, val, eidx) if (hx) { \
    if (myCnt == 0)      { s0v = (val); s0i = (eidx); } \
    else if (myCnt == 1) { s1v = (val); s1i = (eidx); } \
    else if (myCnt == 2) { s2v = (val); s2i = (eidx); } \
    else if (myCnt == 3) { s3v = (val); s3i = (eidx); } \
    ++myCnt; }
            CAPT(h0, v.x, e0 + 0u)
            CAPT(h1, v.y, e0 + 1u)
            CAPT(h2, v.z, e0 + 2u)
            CAPT(h3, v.w, e0 + 3u)
#undef CAPT
        }
        ov[i] = o;
    }

    uint2* __restrict__ ovfp = (uint2*)(ws + OVFP_OFF);
#define PUSHP(val, eidx) { \
    uint32_t p_ = atomicAdd(&cnt, 1u); \
    uint2 pr_ = make_uint2((val), (eidx)); \
    if (p_ < STG_CAP) stage[p_] = pr_; \
    else { uint32_t g_ = atomicAdd(&ws[SCL_OFF + 5], 1u); \
           if (g_ < OVFP_CAP) ovfp[g_] = pr_; } }

    // scalar tail (n & 3), block 0
    if (blockIdx.x == 0) {
        for (long long idx = (n4 << 2) + threadIdx.x; idx < n; idx += NTHR) {
            uint32_t v = x[idx];
            uint32_t u = v & MASK31;
            myHi += (uint32_t)(u >= uHi);
            if (u - uLo < span) PUSHP(v, (uint32_t)idx)
            out[idx] = (u >= uHi) ? v : 0u;
        }
    }

    if (myCnt <= 4u) {
        if (myCnt > 0u) PUSHP(s0v, s0i)
        if (myCnt > 1u) PUSHP(s1v, s1i)
        if (myCnt > 2u) PUSHP(s2v, s2i)
        if (myCnt > 3u) PUSHP(s3v, s3i)
    } else {
        // overflow (~P=2e-4/thread): rescan my own iterations (L3-warm)
        for (long long i = i0; i < n4; i += stride) {
            v4u v = xv[i];
            uint32_t e0 = (uint32_t)(i << 2);
            uint32_t u;
            u = v.x & MASK31; if (u - uLo < span) PUSHP(v.x, e0 + 0u)
            u = v.y & MASK31; if (u - uLo < span) PUSHP(v.y, e0 + 1u)
            u = v.z & MASK31; if (u - uLo < span) PUSHP(v.z, e0 + 2u)
            u = v.w & MASK31; if (u - uLo < span) PUSHP(v.w, e0 + 3u)
        }
    }
#undef PUSHP

    for (int o = 32; o > 0; o >>= 1) myHi += __shfl_down(myHi, o);
    if ((threadIdx.x & 63) == 0) redHi[threadIdx.x >> 6] = myHi;
    __syncthreads();
    if (threadIdx.x == 0) {
        uint32_t tot = 0;
        for (int w = 0; w < NTHR / 64; ++w) tot += redHi[w];
        ws[HIC_OFF + blockIdx.x] = tot;
        uint32_t c = cnt < STG_CAP ? cnt : STG_CAP;
        cnt = c;
        ws[PCN_OFF + blockIdx.x] = c;
    }
    __syncthreads();
    uint2* __restrict__ seg = (uint2*)(ws + PAIRS_OFF) + (size_t)blockIdx.x * SEG_CAP;
    uint32_t c = cnt;
    for (uint32_t q = threadIdx.x; q < c; q += NTHR) seg[q] = stage[q];
}

// ---- cooperative refine: hist -> sync -> redundant select -> fixup ->
//      sync -> block-0 exact stable rank ---------------------------------------
__global__ void refine_kernel(uint32_t* __restrict__ ws, uint32_t k,
                              uint32_t* __restrict__ out) {
    __shared__ uint32_t smem[2 * CMP_CAP];   // 32 KB: lh (phase A/B) / l3s (D)
    __shared__ uint32_t csum[NTHR];
    __shared__ uint32_t cpre[NTHR];
    __shared__ uint32_t sBase2, sRem2, sKp;
    uint32_t* lh = smem;
    uint2* l3s = (uint2*)smem;
    const uint32_t uLo = ws[SCL_OFF + 0], shift1 = ws[SCL_OFF + 2];
    const uint2* pairs = (const uint2*)(ws + PAIRS_OFF);
    uint32_t* cmp = ws + CMP_OFF;

    // ---- phase A: candidate histogram ----
    for (int i = threadIdx.x; i < CH_BINS; i += NTHR) lh[i] = 0;
    __syncthreads();
    for (int g = 0; g < NBLK_MAIN / 256; ++g) {
        uint32_t sidx = blockIdx.x + (uint32_t)g * 256u;
        uint32_t c = ws[PCN_OFF + sidx];
        const uint2* seg = pairs + (size_t)sidx * SEG_CAP;
        for (uint32_t i = threadIdx.x; i < c; i += NTHR) {
            uint32_t u = seg[i].x & MASK31;
            atomicAdd(&lh[((u - uLo) >> shift1) & (CH_BINS - 1)], 1u);
        }
    }
    if (blockIdx.x == 0) {   // overflow pairs
        uint32_t c = ws[SCL_OFF + 5]; if (c > OVFP_CAP) c = OVFP_CAP;
        const uint2* ovfp = (const uint2*)(ws + OVFP_OFF);
        for (uint32_t i = threadIdx.x; i < c; i += NTHR) {
            uint32_t u = ovfp[i].x & MASK31;
            atomicAdd(&lh[((u - uLo) >> shift1) & (CH_BINS - 1)], 1u);
        }
    }
    __syncthreads();
    for (int i = threadIdx.x; i < CH_BINS; i += NTHR)
        if (lh[i]) atomicAdd(&ws[CH_OFF + i], lh[i]);

    cg::this_grid().sync();

    // ---- phase B: redundant per-block sub-bin select ----
    for (int i = threadIdx.x; i < CH_BINS; i += NTHR)
        lh[i] = atomicAdd(&ws[CH_OFF + i], 0u);
    uint32_t part = 0;
    for (int i = threadIdx.x; i < NBLK_MAIN; i += NTHR) part += ws[HIC_OFF + i];
    for (int o = 32; o > 0; o >>= 1) part += __shfl_down(part, o);
    csum[threadIdx.x] = 0;
    __syncthreads();
    if ((threadIdx.x & 63) == 0) csum[threadIdx.x >> 6] = part;
    __syncthreads();
    uint32_t cntHi = csum[0] + csum[1] + csum[2] + csum[3];
    __syncthreads();
    uint32_t s = 0;
    for (int i = 0; i < 16; ++i) s += lh[threadIdx.x * 16 + i];
    csum[threadIdx.x] = s;
    __syncthreads();
    if (threadIdx.x == 0) {
        uint32_t run = 0;
        for (int c = NTHR - 1; c >= 0; --c) { cpre[c] = run; run += csum[c]; }
        uint32_t total = cpre[0] + csum[0];
        uint32_t kp = (k > cntHi) ? (k - cntHi) : 1u;
        if (kp > total) kp = total;
        if (kp < 1u) kp = 1u;
        sKp = kp;
        sBase2 = uLo; sRem2 = 1u;   // fallback
    }
    __syncthreads();
    uint32_t kp = sKp;
    if (cpre[threadIdx.x] < kp && kp <= cpre[threadIdx.x] + csum[threadIdx.x]) {
        uint32_t excl = cpre[threadIdx.x];
        for (int bb = threadIdx.x * 16 + 15; bb >= threadIdx.x * 16; --bb) {
            uint32_t cnt = lh[bb];
            if (excl + cnt >= kp) {
                sBase2 = uLo + (((uint32_t)bb) << shift1);
                sRem2 = kp - excl;
                break;
            }
            excl += cnt;
        }
    }
    __syncthreads();
    const uint32_t base2 = sBase2, rem2 = sRem2;
    const uint32_t width = 1u << shift1;
    const uint32_t tHi2 = base2 + width;

    // ---- phase C: fixup own segments + compact in-sub-bin ----
#define PROC(pr) { \
    uint32_t u_ = (pr).x & MASK31; \
    if (u_ >= tHi2) { out[(pr).y] = (pr).x; } \
    else if (u_ - base2 < width) { \
        uint32_t p_ = atomicAdd(&ws[SCL_OFF + 9], 1u); \
        if (p_ < CMP_CAP) { \
            atomicExch(&cmp[2 * p_], (pr).x); \
            atomicExch(&cmp[2 * p_ + 1], (pr).y); } } }
    for (int g = 0; g < NBLK_MAIN / 256; ++g) {
        uint32_t sidx = blockIdx.x + (uint32_t)g * 256u;
        uint32_t c = ws[PCN_OFF + sidx];
        const uint2* seg = pairs + (size_t)sidx * SEG_CAP;
        for (uint32_t i = threadIdx.x; i < c; i += NTHR) {
            uint2 pr = seg[i];
            PROC(pr)
        }
    }
    if (blockIdx.x == 0) {   // overflow pairs
        uint32_t c = ws[SCL_OFF + 5]; if (c > OVFP_CAP) c = OVFP_CAP;
        const uint2* ovfp = (const uint2*)(ws + OVFP_OFF);
        for (uint32_t i = threadIdx.x; i < c; i += NTHR) {
            uint2 pr = ovfp[i];
            PROC(pr)
        }
    }
#undef PROC

    cg::this_grid().sync();

    // ---- phase D: block 0 exact stable rank over compact set ----
    if (blockIdx.x != 0) return;
    uint32_t c3 = atomicAdd(&ws[SCL_OFF + 9], 0u);
    if (c3 > CMP_CAP) c3 = CMP_CAP;
    for (uint32_t i = threadIdx.x; i < c3; i += NTHR) {
        uint2 pr;
        pr.x = atomicAdd(&cmp[2 * i], 0u);
        pr.y = atomicAdd(&cmp[2 * i + 1], 0u);
        l3s[i] = pr;     // aliases lh: phase A/B data dead by now
    }
    __syncthreads();
    for (uint32_t i = threadIdx.x; i < c3; i += NTHR) {
        uint2 me = l3s[i];
        uint32_t u = me.x & MASK31;
        uint32_t rank = 0;
        for (uint32_t p = 0; p < c3; ++p) {
            uint2 q2 = l3s[p];
            uint32_t up = q2.x & MASK31;
            rank += (up > u || (up == u && q2.y < me.y)) ? 1u : 0u;
        }
        if (rank < rem2) out[me.y] = me.x;
    }
}

extern "C" void kernel_launch(void* const* d_in, const int* in_sizes, int n_in,
                              void* d_out, int out_size, void* d_ws, size_t ws_size,
                              hipStream_t stream) {
    const uint32_t* x = (const uint32_t*)d_in[0];
    uint32_t* out = (uint32_t*)d_out;
    uint32_t* ws = (uint32_t*)d_ws;
    long long n = (long long)in_sizes[0];

    const double ratio = 0.5;  // SPARSE_COMPRESSION_RATIO
    long long k = (long long)((double)n * (1.0 - ratio));
    if (k < 1) k = 1;
    if (k > n) k = n;

    long long n4 = n >> 2;
    long long S = (n4 >> 5) << 2;            // sampled elements (1/32 of n)
    if (S < 4) S = (n4 << 2);
    long long ks = (long long)((double)k * ((double)S / (double)n));
    long long M = (long long)(9.0 * sqrt((double)S * 0.25)) + 64;  // ~9 sigma
    uint32_t ksmM = (uint32_t)((ks - M) < 1 ? 1 : (ks - M));
    uint32_t kspM = (uint32_t)((ks + M) > S ? S : (ks + M));

    zero_ws_kernel<<<(ZERO_WORDS + NTHR - 1) / NTHR, NTHR, 0, stream>>>(ws);
    sample_bracket_kernel<<<256, NTHR, 0, stream>>>((const v4u*)x, n4, ws, ksmM, kspM);
    fused_main_kernel<<<NBLK_MAIN, NTHR, 0, stream>>>(x, out, n, ws);

    uint32_t k32 = (uint32_t)k;
    void* args[] = { (void*)&ws, (void*)&k32, (void*)&out };
    hipLaunchCooperativeKernel((const void*)refine_kernel, dim3(256), dim3(NTHR),
                               args, 0, stream);
}

// Round 17
// 141.645 us; speedup vs baseline: 1.3653x; 1.3653x over previous
//
#include <hip/hip_runtime.h>
#include <stdint.h>
#include <math.h>

// ----------------------------------------------------------------------------
// SparseKVCache: keep top-k by |x| (k = n/2), zero the rest. Exact.
// R17 = R15 with cand_hist_sel ELIMINATED: fused_main histograms each
// candidate at push time (1 scattered global atomic per candidate, ~300K
// total, post-loop); gather_fixup does the sub-bin select REDUNDANTLY per
// block from CH/HIC via plain loads (previous-kernel writes are coherent
// across the kernel boundary), then fixup + compact + last-block exact
// stable rank (ties: smallest index). 4 launches. Deterministic.
//   zero_ws -> sample_bracket -> fused_main -> gather_fixup
// (R16 lesson: cooperative grid.sync costs ~35-40us each on MI355X --
//  launch gaps are cheaper; reverted.)
// ----------------------------------------------------------------------------

#define NTHR 256
#define MASK31 0x7fffffffu

typedef unsigned int v4u __attribute__((ext_vector_type(4)));

// ---- ws layout (uint32 words) ----
#define SH_OFF    0            // 8192-bin sample histogram (bits 30..18)
#define SH_BINS   8192
#define CH_OFF    8192         // 4096-bin candidate histogram
#define CH_BINS   4096
#define SCL_OFF   12288        // scalars:
//  [0]=uLo [1]=uHi [2]=shift1 [5]=ovfPairCnt [7]=done1 [9]=cmpCnt [10]=done3
#define ZERO_WORDS 12320
#define HIC_OFF   12320        // per-block hi counts (4096)
#define PCN_OFF   16416        // per-block pair counts (4096)
#define OVFP_OFF  20512        // overflow pairs (even => 8B aligned)
#define OVFP_CAP  16384
#define CMP_OFF   53536        // compact in-sub-bin pairs (even => 8B aligned)
#define CMP_CAP   4096
#define PAIRS_OFF 131072       // per-block pair segments: 4096 x 1024 pairs
#define SEG_CAP   1024
#define NBLK_MAIN 4096
#define STG_CAP   1024         // LDS pair stage (8 KB)

__global__ void zero_ws_kernel(uint32_t* __restrict__ ws) {
    int i = blockIdx.x * blockDim.x + threadIdx.x;
    if (i < ZERO_WORDS) ws[i] = 0;
}

// ---- sample hist (1/32 of data, 8KB runs) + last-block bracket select ------
__global__ void sample_bracket_kernel(const v4u* __restrict__ xv, long long n4,
                                      uint32_t* __restrict__ ws,
                                      uint32_t ksmM, uint32_t kspM) {
    __shared__ uint32_t lh[SH_BINS];
    __shared__ uint32_t csum[NTHR];
    __shared__ uint32_t cpre[NTHR];
    __shared__ int sBHi, sB1, amLast;
    for (int i = threadIdx.x; i < SH_BINS; i += NTHR) lh[i] = 0;
    __syncthreads();
    long long S4 = n4 >> 5;                 // sampled uint4 count (1/32)
    long long T = (long long)gridDim.x * NTHR;
    for (long long s = (long long)blockIdx.x * NTHR + threadIdx.x; s < S4; s += T) {
        long long idx4 = ((s >> 9) << 14) | (s & 511);  // 512-uint4 runs /16384
        if (idx4 < n4) {
            v4u v = xv[idx4];
            atomicAdd(&lh[(v.x & MASK31) >> 18], 1u);
            atomicAdd(&lh[(v.y & MASK31) >> 18], 1u);
            atomicAdd(&lh[(v.z & MASK31) >> 18], 1u);
            atomicAdd(&lh[(v.w & MASK31) >> 18], 1u);
        }
    }
    __syncthreads();
    for (int i = threadIdx.x; i < SH_BINS; i += NTHR)
        if (lh[i]) atomicAdd(&ws[SH_OFF + i], lh[i]);
    __syncthreads();   // drains vmcnt: this block's atomics are device-visible
    if (threadIdx.x == 0) {
        uint32_t old = atomicAdd(&ws[SCL_OFF + 7], 1u);
        amLast = (old == gridDim.x - 1u) ? 1 : 0;
        sBHi = -1; sB1 = -1;
    }
    __syncthreads();
    if (!amLast) return;
    for (int i = threadIdx.x; i < SH_BINS; i += NTHR)
        lh[i] = atomicAdd(&ws[SH_OFF + i], 0u);
    __syncthreads();
    uint32_t s = 0;
    for (int i = 0; i < 32; ++i) s += lh[threadIdx.x * 32 + i];
    csum[threadIdx.x] = s;
    __syncthreads();
    if (threadIdx.x == 0) {
        uint32_t run = 0;
        for (int c = NTHR - 1; c >= 0; --c) { cpre[c] = run; run += csum[c]; }
    }
    __syncthreads();
    {
        int c = threadIdx.x;
        int hitHi = -1, hitB1 = -1;
        uint32_t excl = cpre[c];
        for (int bb = c * 32 + 31; bb >= c * 32; --bb) {
            uint32_t cnt = lh[bb];
            uint32_t incl = excl + cnt;
            if (hitHi < 0 && incl >= ksmM) hitHi = bb;
            if (hitB1 < 0 && excl >= kspM) hitB1 = bb;
            excl = incl;
        }
        if (hitHi >= 0) atomicMax(&sBHi, hitHi);
        if (hitB1 >= 0) atomicMax(&sB1, hitB1);
    }
    __syncthreads();
    if (threadIdx.x == 0) {
        int bHi = sBHi < 0 ? 0 : sBHi;
        int bLo = sB1 + 1;
        if (bLo > bHi) bLo = bHi;
        if (bLo < 0) bLo = 0;
        int sbins = bHi - bLo + 1;
        int clog = 0; while ((1 << clog) < sbins) ++clog;
        int spanBits = 18 + clog;
        int shift1 = spanBits - 12;            // 4096 bins over the span
        if (shift1 < 0) shift1 = 0;
        ws[SCL_OFF + 0] = ((uint32_t)bLo) << 18;          // uLo
        ws[SCL_OFF + 1] = ((uint32_t)(bHi + 1)) << 18;    // uHi (exclusive)
        ws[SCL_OFF + 2] = (uint32_t)shift1;
    }
}

// ---- fused full pass: register candidate capture + push-time CH hist -------
__global__ void fused_main_kernel(const uint32_t* __restrict__ x,
                                  uint32_t* __restrict__ out, long long n,
                                  uint32_t* __restrict__ ws) {
    __shared__ uint2 stage[STG_CAP];     // 8 KB
    __shared__ uint32_t cnt, redHi[NTHR / 64];
    const uint32_t uLo = ws[SCL_OFF + 0];
    const uint32_t uHi = ws[SCL_OFF + 1];
    const uint32_t shift1 = ws[SCL_OFF + 2];
    const uint32_t span = uHi - uLo;
    if (threadIdx.x == 0) cnt = 0u;
    __syncthreads();

    const v4u* __restrict__ xv = (const v4u*)x;
    v4u* __restrict__ ov = (v4u*)out;
    long long n4 = n >> 2;
    const long long stride = (long long)gridDim.x * NTHR;
    const long long i0 = (long long)blockIdx.x * NTHR + threadIdx.x;

    uint32_t myHi = 0;
    uint32_t myCnt = 0;
    uint32_t s0v = 0, s0i = 0, s1v = 0, s1i = 0;
    uint32_t s2v = 0, s2i = 0, s3v = 0, s3i = 0;

    for (long long i = i0; i < n4; i += stride) {
        v4u v = xv[i];
        uint32_t c0 = v.x & MASK31, c1 = v.y & MASK31;
        uint32_t c2 = v.z & MASK31, c3 = v.w & MASK31;
        myHi += (uint32_t)(c0 >= uHi) + (uint32_t)(c1 >= uHi)
              + (uint32_t)(c2 >= uHi) + (uint32_t)(c3 >= uHi);
        v4u o;
        o.x = (c0 >= uHi) ? v.x : 0u;
        o.y = (c1 >= uHi) ? v.y : 0u;
        o.z = (c2 >= uHi) ? v.z : 0u;
        o.w = (c3 >= uHi) ? v.w : 0u;
        uint32_t h0 = (c0 - uLo) < span ? 1u : 0u;
        uint32_t h1 = (c1 - uLo) < span ? 1u : 0u;
        uint32_t h2 = (c2 - uLo) < span ? 1u : 0u;
        uint32_t h3 = (c3 - uLo) < span ? 1u : 0u;
        if (h0 | h1 | h2 | h3) {
            uint32_t e0 = (uint32_t)(i << 2);
#define CAPT(hx, val, eidx) if (hx) { \
    if (myCnt == 0)      { s0v = (val); s0i = (eidx); } \
    else if (myCnt == 1) { s1v = (val); s1i = (eidx); } \
    else if (myCnt == 2) { s2v = (val); s2i = (eidx); } \
    else if (myCnt == 3) { s3v = (val); s3i = (eidx); } \
    ++myCnt; }
            CAPT(h0, v.x, e0 + 0u)
            CAPT(h1, v.y, e0 + 1u)
            CAPT(h2, v.z, e0 + 2u)
            CAPT(h3, v.w, e0 + 3u)
#undef CAPT
        }
        ov[i] = o;
    }

    uint2* __restrict__ ovfp = (uint2*)(ws + OVFP_OFF);
    // push + histogram the candidate at the same time (CH for the select)
#define PUSHP(val, eidx) { \
    uint32_t p_ = atomicAdd(&cnt, 1u); \
    uint2 pr_ = make_uint2((val), (eidx)); \
    uint32_t bin_ = ((((val) & MASK31) - uLo) >> shift1) & (CH_BINS - 1); \
    atomicAdd(&ws[CH_OFF + bin_], 1u); \
    if (p_ < STG_CAP) stage[p_] = pr_; \
    else { uint32_t g_ = atomicAdd(&ws[SCL_OFF + 5], 1u); \
           if (g_ < OVFP_CAP) ovfp[g_] = pr_; } }

    // scalar tail (n & 3), block 0
    if (blockIdx.x == 0) {
        for (long long idx = (n4 << 2) + threadIdx.x; idx < n; idx += NTHR) {
            uint32_t v = x[idx];
            uint32_t u = v & MASK31;
            myHi += (uint32_t)(u >= uHi);
            if (u - uLo < span) PUSHP(v, (uint32_t)idx)
            out[idx] = (u >= uHi) ? v : 0u;
        }
    }

    if (myCnt <= 4u) {
        if (myCnt > 0u) PUSHP(s0v, s0i)
        if (myCnt > 1u) PUSHP(s1v, s1i)
        if (myCnt > 2u) PUSHP(s2v, s2i)
        if (myCnt > 3u) PUSHP(s3v, s3i)
    } else {
        // overflow (~P=2e-4/thread): rescan my own iterations (L3-warm)
        for (long long i = i0; i < n4; i += stride) {
            v4u v = xv[i];
            uint32_t e0 = (uint32_t)(i << 2);
            uint32_t u;
            u = v.x & MASK31; if (u - uLo < span) PUSHP(v.x, e0 + 0u)
            u = v.y & MASK31; if (u - uLo < span) PUSHP(v.y, e0 + 1u)
            u = v.z & MASK31; if (u - uLo < span) PUSHP(v.z, e0 + 2u)
            u = v.w & MASK31; if (u - uLo < span) PUSHP(v.w, e0 + 3u)
        }
    }
#undef PUSHP

    for (int o = 32; o > 0; o >>= 1) myHi += __shfl_down(myHi, o);
    if ((threadIdx.x & 63) == 0) redHi[threadIdx.x >> 6] = myHi;
    __syncthreads();
    if (threadIdx.x == 0) {
        uint32_t tot = 0;
        for (int w = 0; w < NTHR / 64; ++w) tot += redHi[w];
        ws[HIC_OFF + blockIdx.x] = tot;
        uint32_t c = cnt < STG_CAP ? cnt : STG_CAP;
        cnt = c;
        ws[PCN_OFF + blockIdx.x] = c;
    }
    __syncthreads();
    uint2* __restrict__ seg = (uint2*)(ws + PAIRS_OFF) + (size_t)blockIdx.x * SEG_CAP;
    uint32_t c = cnt;
    for (uint32_t q = threadIdx.x; q < c; q += NTHR) seg[q] = stage[q];
}

// ---- gather_fixup: redundant per-block select (plain loads of CH/HIC from
//      previous kernel) -> own-segment fixup + compact -> last-block rank ----
__global__ void gather_fixup_kernel(uint32_t* __restrict__ ws, uint32_t k,
                                    uint32_t* __restrict__ out) {
    __shared__ uint32_t smem[2 * CMP_CAP];   // 32 KB: lh (select) / l3s (rank)
    __shared__ uint32_t csum[NTHR];
    __shared__ uint32_t cpre[NTHR];
    __shared__ uint32_t sBase2, sRem2, sKp;
    __shared__ int amLast;
    uint32_t* lh = smem;
    uint2* l3s = (uint2*)smem;
    const uint32_t uLo = ws[SCL_OFF + 0], shift1 = ws[SCL_OFF + 2];
    const uint2* pairs = (const uint2*)(ws + PAIRS_OFF);
    uint32_t* cmp = ws + CMP_OFF;

    // ---- select phase (redundant per block; CH/HIC via plain loads) ----
    for (int i = threadIdx.x; i < CH_BINS; i += NTHR) lh[i] = ws[CH_OFF + i];
    uint32_t part = 0;
    for (int i = threadIdx.x; i < NBLK_MAIN; i += NTHR) part += ws[HIC_OFF + i];
    for (int o = 32; o > 0; o >>= 1) part += __shfl_down(part, o);
    csum[threadIdx.x] = 0;
    __syncthreads();
    if ((threadIdx.x & 63) == 0) csum[threadIdx.x >> 6] = part;
    __syncthreads();
    uint32_t cntHi = csum[0] + csum[1] + csum[2] + csum[3];
    __syncthreads();
    uint32_t s = 0;
    for (int i = 0; i < 16; ++i) s += lh[threadIdx.x * 16 + i];
    csum[threadIdx.x] = s;
    __syncthreads();
    if (threadIdx.x == 0) {
        uint32_t run = 0;
        for (int c = NTHR - 1; c >= 0; --c) { cpre[c] = run; run += csum[c]; }
        uint32_t total = cpre[0] + csum[0];
        uint32_t kp = (k > cntHi) ? (k - cntHi) : 1u;
        if (kp > total) kp = total;
        if (kp < 1u) kp = 1u;
        sKp = kp;
        sBase2 = uLo; sRem2 = 1u;   // fallback
    }
    __syncthreads();
    uint32_t kp = sKp;
    if (cpre[threadIdx.x] < kp && kp <= cpre[threadIdx.x] + csum[threadIdx.x]) {
        uint32_t excl = cpre[threadIdx.x];
        for (int bb = threadIdx.x * 16 + 15; bb >= threadIdx.x * 16; --bb) {
            uint32_t cnt = lh[bb];
            if (excl + cnt >= kp) {
                sBase2 = uLo + (((uint32_t)bb) << shift1);
                sRem2 = kp - excl;
                break;
            }
            excl += cnt;
        }
    }
    __syncthreads();
    const uint32_t base2 = sBase2, rem2 = sRem2;
    const uint32_t width = 1u << shift1;
    const uint32_t tHi2 = base2 + width;

    // ---- fixup phase: scan own 16 segments, restore keeps, compact in-bin --
#define PROC(pr) { \
    uint32_t u_ = (pr).x & MASK31; \
    if (u_ >= tHi2) { out[(pr).y] = (pr).x; } \
    else if (u_ - base2 < width) { \
        uint32_t p_ = atomicAdd(&ws[SCL_OFF + 9], 1u); \
        if (p_ < CMP_CAP) { \
            atomicExch(&cmp[2 * p_], (pr).x); \
            atomicExch(&cmp[2 * p_ + 1], (pr).y); } } }
    for (int g = 0; g < NBLK_MAIN / 256; ++g) {
        uint32_t sidx = blockIdx.x + (uint32_t)g * 256u;
        uint32_t c = ws[PCN_OFF + sidx];
        const uint2* seg = pairs + (size_t)sidx * SEG_CAP;
        for (uint32_t i = threadIdx.x; i < c; i += NTHR) {
            uint2 pr = seg[i];
            PROC(pr)
        }
    }
    if (blockIdx.x == 0) {   // overflow pairs
        uint32_t c = ws[SCL_OFF + 5]; if (c > OVFP_CAP) c = OVFP_CAP;
        const uint2* ovfp = (const uint2*)(ws + OVFP_OFF);
        for (uint32_t i = threadIdx.x; i < c; i += NTHR) {
            uint2 pr = ovfp[i];
            PROC(pr)
        }
    }
#undef PROC
    __syncthreads();   // drain: this block's atomics device-visible
    if (threadIdx.x == 0) {
        uint32_t old = atomicAdd(&ws[SCL_OFF + 10], 1u);
        amLast = (old == gridDim.x - 1u) ? 1 : 0;
    }
    __syncthreads();
    if (!amLast) return;
    // ---- last block: exact stable rank over the compact in-sub-bin set ----
    uint32_t c3 = atomicAdd(&ws[SCL_OFF + 9], 0u);
    if (c3 > CMP_CAP) c3 = CMP_CAP;
    for (uint32_t i = threadIdx.x; i < c3; i += NTHR) {
        uint2 pr;
        pr.x = atomicAdd(&cmp[2 * i], 0u);
        pr.y = atomicAdd(&cmp[2 * i + 1], 0u);
        l3s[i] = pr;     // aliases lh: select data dead by now
    }
    __syncthreads();
    for (uint32_t i = threadIdx.x; i < c3; i += NTHR) {
        uint2 me = l3s[i];
        uint32_t u = me.x & MASK31;
        uint32_t rank = 0;
        for (uint32_t p = 0; p < c3; ++p) {
            uint2 q2 = l3s[p];
            uint32_t up = q2.x & MASK31;
            rank += (up > u || (up == u && q2.y < me.y)) ? 1u : 0u;
        }
        if (rank < rem2) out[me.y] = me.x;
    }
}

extern "C" void kernel_launch(void* const* d_in, const int* in_sizes, int n_in,
                              void* d_out, int out_size, void* d_ws, size_t ws_size,
                              hipStream_t stream) {
    const uint32_t* x = (const uint32_t*)d_in[0];
    uint32_t* out = (uint32_t*)d_out;
    uint32_t* ws = (uint32_t*)d_ws;
    long long n = (long long)in_sizes[0];

    const double ratio = 0.5;  // SPARSE_COMPRESSION_RATIO
    long long k = (long long)((double)n * (1.0 - ratio));
    if (k < 1) k = 1;
    if (k > n) k = n;

    long long n4 = n >> 2;
    long long S = (n4 >> 5) << 2;            // sampled elements (1/32 of n)
    if (S < 4) S = (n4 << 2);
    long long ks = (long long)((double)k * ((double)S / (double)n));
    long long M = (long long)(9.0 * sqrt((double)S * 0.25)) + 64;  // ~9 sigma
    uint32_t ksmM = (uint32_t)((ks - M) < 1 ? 1 : (ks - M));
    uint32_t kspM = (uint32_t)((ks + M) > S ? S : (ks + M));

    zero_ws_kernel<<<(ZERO_WORDS + NTHR - 1) / NTHR, NTHR, 0, stream>>>(ws);
    sample_bracket_kernel<<<256, NTHR, 0, stream>>>((const v4u*)x, n4, ws, ksmM, kspM);
    fused_main_kernel<<<NBLK_MAIN, NTHR, 0, stream>>>(x, out, n, ws);
    gather_fixup_kernel<<<256, NTHR, 0, stream>>>(ws, (uint32_t)k, out);
}

// Round 18
// 123.763 us; speedup vs baseline: 1.5626x; 1.1445x over previous
//
#include <hip/hip_runtime.h>
#include <stdint.h>
#include <math.h>

// ----------------------------------------------------------------------------
// SparseKVCache: keep top-k by |x| (k = n/2), zero the rest. Exact.
// R18 = R15 (best: 134.1us) + two micro-fixes:
//   (a) NONTEMPORAL stores in fused hot loop -- writes stop evicting the
//       read stream from L3 (R15 showed 50% read L3-hit; writes compete).
//   (b) sample_bracket grid 256->64 -- its 8192-bin global merge had ~60-way
//       same-address atomic contention (the R9-class cost); 4x fewer blocks.
// Chain: zero_ws -> sample_bracket -> fused_main -> cand_hist_sel ->
//        gather_fixup. No same-address global atomics in hot paths.
// (R16: cooperative grid.sync ~35-40us each => reverted. R17: push-time CH
//  hist = 73-way same-address contention => reverted.)
// ----------------------------------------------------------------------------

#define NTHR 256
#define MASK31 0x7fffffffu

typedef unsigned int v4u __attribute__((ext_vector_type(4)));

// ---- ws layout (uint32 words) ----
#define SH_OFF    0            // 8192-bin sample histogram (bits 30..18)
#define SH_BINS   8192
#define CH_OFF    8192         // 4096-bin candidate histogram
#define CH_BINS   4096
#define SCL_OFF   12288        // scalars:
//  [0]=uLo [1]=uHi [2]=shift1 [3]=base2 [4]=rem2 [5]=ovfPairCnt
//  [7]=done1 [8]=done2 [9]=cmpCnt [10]=done3
#define ZERO_WORDS 12320
#define HIC_OFF   12320        // per-block hi counts (4096)
#define PCN_OFF   16416        // per-block pair counts (4096)
#define OVFP_OFF  20512        // overflow pairs (even => 8B aligned)
#define OVFP_CAP  16384
#define CMP_OFF   53536        // compact in-sub-bin pairs (even => 8B aligned)
#define CMP_CAP   4096
#define PAIRS_OFF 131072       // per-block pair segments: 4096 x 1024 pairs
#define SEG_CAP   1024
#define NBLK_MAIN 4096
#define STG_CAP   1024         // LDS pair stage (8 KB)

__global__ void zero_ws_kernel(uint32_t* __restrict__ ws) {
    int i = blockIdx.x * blockDim.x + threadIdx.x;
    if (i < ZERO_WORDS) ws[i] = 0;
}

// ---- sample hist (1/32 of data, 8KB runs) + last-block bracket select ------
__global__ void sample_bracket_kernel(const v4u* __restrict__ xv, long long n4,
                                      uint32_t* __restrict__ ws,
                                      uint32_t ksmM, uint32_t kspM) {
    __shared__ uint32_t lh[SH_BINS];
    __shared__ uint32_t csum[NTHR];
    __shared__ uint32_t cpre[NTHR];
    __shared__ int sBHi, sB1, amLast;
    for (int i = threadIdx.x; i < SH_BINS; i += NTHR) lh[i] = 0;
    __syncthreads();
    long long S4 = n4 >> 5;                 // sampled uint4 count (1/32)
    long long T = (long long)gridDim.x * NTHR;
    for (long long s = (long long)blockIdx.x * NTHR + threadIdx.x; s < S4; s += T) {
        long long idx4 = ((s >> 9) << 14) | (s & 511);  // 512-uint4 runs /16384
        if (idx4 < n4) {
            v4u v = xv[idx4];
            atomicAdd(&lh[(v.x & MASK31) >> 18], 1u);
            atomicAdd(&lh[(v.y & MASK31) >> 18], 1u);
            atomicAdd(&lh[(v.z & MASK31) >> 18], 1u);
            atomicAdd(&lh[(v.w & MASK31) >> 18], 1u);
        }
    }
    __syncthreads();
    for (int i = threadIdx.x; i < SH_BINS; i += NTHR)
        if (lh[i]) atomicAdd(&ws[SH_OFF + i], lh[i]);
    __syncthreads();   // drains vmcnt: this block's atomics are device-visible
    if (threadIdx.x == 0) {
        uint32_t old = atomicAdd(&ws[SCL_OFF + 7], 1u);
        amLast = (old == gridDim.x - 1u) ? 1 : 0;
        sBHi = -1; sB1 = -1;
    }
    __syncthreads();
    if (!amLast) return;
    for (int i = threadIdx.x; i < SH_BINS; i += NTHR)
        lh[i] = atomicAdd(&ws[SH_OFF + i], 0u);
    __syncthreads();
    uint32_t s = 0;
    for (int i = 0; i < 32; ++i) s += lh[threadIdx.x * 32 + i];
    csum[threadIdx.x] = s;
    __syncthreads();
    if (threadIdx.x == 0) {
        uint32_t run = 0;
        for (int c = NTHR - 1; c >= 0; --c) { cpre[c] = run; run += csum[c]; }
    }
    __syncthreads();
    {
        int c = threadIdx.x;
        int hitHi = -1, hitB1 = -1;
        uint32_t excl = cpre[c];
        for (int bb = c * 32 + 31; bb >= c * 32; --bb) {
            uint32_t cnt = lh[bb];
            uint32_t incl = excl + cnt;
            if (hitHi < 0 && incl >= ksmM) hitHi = bb;
            if (hitB1 < 0 && excl >= kspM) hitB1 = bb;
            excl = incl;
        }
        if (hitHi >= 0) atomicMax(&sBHi, hitHi);
        if (hitB1 >= 0) atomicMax(&sB1, hitB1);
    }
    __syncthreads();
    if (threadIdx.x == 0) {
        int bHi = sBHi < 0 ? 0 : sBHi;
        int bLo = sB1 + 1;
        if (bLo > bHi) bLo = bHi;
        if (bLo < 0) bLo = 0;
        int sbins = bHi - bLo + 1;
        int clog = 0; while ((1 << clog) < sbins) ++clog;
        int spanBits = 18 + clog;
        int shift1 = spanBits - 12;            // 4096 bins over the span
        if (shift1 < 0) shift1 = 0;
        ws[SCL_OFF + 0] = ((uint32_t)bLo) << 18;          // uLo
        ws[SCL_OFF + 1] = ((uint32_t)(bHi + 1)) << 18;    // uHi (exclusive)
        ws[SCL_OFF + 2] = (uint32_t)shift1;
    }
}

// ---- fused full pass: register candidate capture; nt stores ----------------
__global__ void fused_main_kernel(const uint32_t* __restrict__ x,
                                  uint32_t* __restrict__ out, long long n,
                                  uint32_t* __restrict__ ws) {
    __shared__ uint2 stage[STG_CAP];     // 8 KB
    __shared__ uint32_t cnt, redHi[NTHR / 64];
    const uint32_t uLo = ws[SCL_OFF + 0];
    const uint32_t uHi = ws[SCL_OFF + 1];
    const uint32_t span = uHi - uLo;
    if (threadIdx.x == 0) cnt = 0u;
    __syncthreads();

    const v4u* __restrict__ xv = (const v4u*)x;
    v4u* __restrict__ ov = (v4u*)out;
    long long n4 = n >> 2;
    const long long stride = (long long)gridDim.x * NTHR;
    const long long i0 = (long long)blockIdx.x * NTHR + threadIdx.x;

    uint32_t myHi = 0;
    uint32_t myCnt = 0;
    uint32_t s0v = 0, s0i = 0, s1v = 0, s1i = 0;
    uint32_t s2v = 0, s2i = 0, s3v = 0, s3i = 0;

    for (long long i = i0; i < n4; i += stride) {
        v4u v = xv[i];
        uint32_t c0 = v.x & MASK31, c1 = v.y & MASK31;
        uint32_t c2 = v.z & MASK31, c3 = v.w & MASK31;
        myHi += (uint32_t)(c0 >= uHi) + (uint32_t)(c1 >= uHi)
              + (uint32_t)(c2 >= uHi) + (uint32_t)(c3 >= uHi);
        v4u o;
        o.x = (c0 >= uHi) ? v.x : 0u;
        o.y = (c1 >= uHi) ? v.y : 0u;
        o.z = (c2 >= uHi) ? v.z : 0u;
        o.w = (c3 >= uHi) ? v.w : 0u;
        uint32_t h0 = (c0 - uLo) < span ? 1u : 0u;
        uint32_t h1 = (c1 - uLo) < span ? 1u : 0u;
        uint32_t h2 = (c2 - uLo) < span ? 1u : 0u;
        uint32_t h3 = (c3 - uLo) < span ? 1u : 0u;
        if (h0 | h1 | h2 | h3) {
            uint32_t e0 = (uint32_t)(i << 2);
#define CAPT(hx, val, eidx) if (hx) { \
    if (myCnt == 0)      { s0v = (val); s0i = (eidx); } \
    else if (myCnt == 1) { s1v = (val); s1i = (eidx); } \
    else if (myCnt == 2) { s2v = (val); s2i = (eidx); } \
    else if (myCnt == 3) { s3v = (val); s3i = (eidx); } \
    ++myCnt; }
            CAPT(h0, v.x, e0 + 0u)
            CAPT(h1, v.y, e0 + 1u)
            CAPT(h2, v.z, e0 + 2u)
            CAPT(h3, v.w, e0 + 3u)
#undef CAPT
        }
        __builtin_nontemporal_store(o, &ov[i]);
    }

    uint2* __restrict__ ovfp = (uint2*)(ws + OVFP_OFF);
#define PUSHP(val, eidx) { \
    uint32_t p_ = atomicAdd(&cnt, 1u); \
    uint2 pr_ = make_uint2((val), (eidx)); \
    if (p_ < STG_CAP) stage[p_] = pr_; \
    else { uint32_t g_ = atomicAdd(&ws[SCL_OFF + 5], 1u); \
           if (g_ < OVFP_CAP) ovfp[g_] = pr_; } }

    // scalar tail (n & 3), block 0
    if (blockIdx.x == 0) {
        for (long long idx = (n4 << 2) + threadIdx.x; idx < n; idx += NTHR) {
            uint32_t v = x[idx];
            uint32_t u = v & MASK31;
            myHi += (uint32_t)(u >= uHi);
            if (u - uLo < span) PUSHP(v, (uint32_t)idx)
            out[idx] = (u >= uHi) ? v : 0u;
        }
    }

    if (myCnt <= 4u) {
        if (myCnt > 0u) PUSHP(s0v, s0i)
        if (myCnt > 1u) PUSHP(s1v, s1i)
        if (myCnt > 2u) PUSHP(s2v, s2i)
        if (myCnt > 3u) PUSHP(s3v, s3i)
    } else {
        // overflow (~P=2e-4/thread): rescan my own iterations (L3-warm)
        for (long long i = i0; i < n4; i += stride) {
            v4u v = xv[i];
            uint32_t e0 = (uint32_t)(i << 2);
            uint32_t u;
            u = v.x & MASK31; if (u - uLo < span) PUSHP(v.x, e0 + 0u)
            u = v.y & MASK31; if (u - uLo < span) PUSHP(v.y, e0 + 1u)
            u = v.z & MASK31; if (u - uLo < span) PUSHP(v.z, e0 + 2u)
            u = v.w & MASK31; if (u - uLo < span) PUSHP(v.w, e0 + 3u)
        }
    }
#undef PUSHP

    for (int o = 32; o > 0; o >>= 1) myHi += __shfl_down(myHi, o);
    if ((threadIdx.x & 63) == 0) redHi[threadIdx.x >> 6] = myHi;
    __syncthreads();
    if (threadIdx.x == 0) {
        uint32_t tot = 0;
        for (int w = 0; w < NTHR / 64; ++w) tot += redHi[w];
        ws[HIC_OFF + blockIdx.x] = tot;
        uint32_t c = cnt < STG_CAP ? cnt : STG_CAP;
        cnt = c;
        ws[PCN_OFF + blockIdx.x] = c;
    }
    __syncthreads();
    uint2* __restrict__ seg = (uint2*)(ws + PAIRS_OFF) + (size_t)blockIdx.x * SEG_CAP;
    uint32_t c = cnt;
    for (uint32_t q = threadIdx.x; q < c; q += NTHR) seg[q] = stage[q];
}

// ---- candidate histogram + last-block sub-bin select ------------------------
__global__ void cand_hist_sel_kernel(uint32_t* __restrict__ ws, uint32_t k) {
    __shared__ uint32_t lh[CH_BINS];
    __shared__ uint32_t csum[NTHR];
    __shared__ uint32_t cpre[NTHR];
    __shared__ int amLast;
    __shared__ uint32_t sBase2, sRem2;
    uint32_t uLo = ws[SCL_OFF + 0], shift1 = ws[SCL_OFF + 2];
    for (int i = threadIdx.x; i < CH_BINS; i += NTHR) lh[i] = 0;
    __syncthreads();
    const uint2* pairs = (const uint2*)(ws + PAIRS_OFF);
    for (int g = 0; g < NBLK_MAIN / 256; ++g) {
        uint32_t sidx = blockIdx.x + (uint32_t)g * 256u;
        uint32_t c = ws[PCN_OFF + sidx];
        const uint2* seg = pairs + (size_t)sidx * SEG_CAP;
        for (uint32_t i = threadIdx.x; i < c; i += NTHR) {
            uint32_t u = seg[i].x & MASK31;
            atomicAdd(&lh[((u - uLo) >> shift1) & (CH_BINS - 1)], 1u);
        }
    }
    if (blockIdx.x == 0) {
        uint32_t c = ws[SCL_OFF + 5]; if (c > OVFP_CAP) c = OVFP_CAP;
        const uint2* ovfp = (const uint2*)(ws + OVFP_OFF);
        for (uint32_t i = threadIdx.x; i < c; i += NTHR) {
            uint32_t u = ovfp[i].x & MASK31;
            atomicAdd(&lh[((u - uLo) >> shift1) & (CH_BINS - 1)], 1u);
        }
    }
    __syncthreads();
    for (int i = threadIdx.x; i < CH_BINS; i += NTHR)
        if (lh[i]) atomicAdd(&ws[CH_OFF + i], lh[i]);
    __syncthreads();   // drain: merges visible
    if (threadIdx.x == 0) {
        uint32_t old = atomicAdd(&ws[SCL_OFF + 8], 1u);
        amLast = (old == gridDim.x - 1u) ? 1 : 0;
    }
    __syncthreads();
    if (!amLast) return;
    for (int i = threadIdx.x; i < CH_BINS; i += NTHR)
        lh[i] = atomicAdd(&ws[CH_OFF + i], 0u);
    uint32_t part = 0;
    for (int i = threadIdx.x; i < NBLK_MAIN; i += NTHR) part += ws[HIC_OFF + i];
    for (int o = 32; o > 0; o >>= 1) part += __shfl_down(part, o);
    csum[threadIdx.x] = 0;
    __syncthreads();
    if ((threadIdx.x & 63) == 0) csum[threadIdx.x >> 6] = part;
    __syncthreads();
    uint32_t cntHi = csum[0] + csum[1] + csum[2] + csum[3];
    __syncthreads();
    uint32_t s = 0;
    for (int i = 0; i < 16; ++i) s += lh[threadIdx.x * 16 + i];
    csum[threadIdx.x] = s;
    __syncthreads();
    __shared__ uint32_t sKp;
    if (threadIdx.x == 0) {
        uint32_t run = 0;
        for (int c = NTHR - 1; c >= 0; --c) { cpre[c] = run; run += csum[c]; }
        uint32_t total = cpre[0] + csum[0];
        uint32_t kp = (k > cntHi) ? (k - cntHi) : 1u;
        if (kp > total) kp = total;
        if (kp < 1u) kp = 1u;
        sKp = kp;
        sBase2 = uLo; sRem2 = 1u;   // fallback
    }
    __syncthreads();
    uint32_t kp = sKp;
    if (cpre[threadIdx.x] < kp && kp <= cpre[threadIdx.x] + csum[threadIdx.x]) {
        uint32_t excl = cpre[threadIdx.x];
        for (int bb = threadIdx.x * 16 + 15; bb >= threadIdx.x * 16; --bb) {
            uint32_t cnt = lh[bb];
            if (excl + cnt >= kp) {
                sBase2 = uLo + (((uint32_t)bb) << shift1);
                sRem2 = kp - excl;
                break;
            }
            excl += cnt;
        }
    }
    __syncthreads();
    if (threadIdx.x == 0) { ws[SCL_OFF + 3] = sBase2; ws[SCL_OFF + 4] = sRem2; }
}

// ---- gather_fixup: own-segment scan + compact; last block ranks compact ----
__global__ void gather_fixup_kernel(uint32_t* __restrict__ ws,
                                    uint32_t* __restrict__ out) {
    __shared__ uint2 l3s[CMP_CAP];   // 32 KB
    __shared__ int amLast;
    uint32_t base2 = ws[SCL_OFF + 3], rem2 = ws[SCL_OFF + 4];
    uint32_t width = 1u << ws[SCL_OFF + 2];
    uint32_t tHi2 = base2 + width;
    const uint2* pairs = (const uint2*)(ws + PAIRS_OFF);
    uint32_t* cmp = ws + CMP_OFF;

#define PROC(pr) { \
    uint32_t u_ = (pr).x & MASK31; \
    if (u_ >= tHi2) { out[(pr).y] = (pr).x; } \
    else if (u_ - base2 < width) { \
        uint32_t p_ = atomicAdd(&ws[SCL_OFF + 9], 1u); \
        if (p_ < CMP_CAP) { \
            atomicExch(&cmp[2 * p_], (pr).x); \
            atomicExch(&cmp[2 * p_ + 1], (pr).y); } } }

    // scan my own 16 segments, thread-strided (coalesced)
    for (int g = 0; g < NBLK_MAIN / 256; ++g) {
        uint32_t sidx = blockIdx.x + (uint32_t)g * 256u;
        uint32_t c = ws[PCN_OFF + sidx];
        const uint2* seg = pairs + (size_t)sidx * SEG_CAP;
        for (uint32_t i = threadIdx.x; i < c; i += NTHR) {
            uint2 pr = seg[i];
            PROC(pr)
        }
    }
    if (blockIdx.x == 0) {   // overflow pairs
        uint32_t c = ws[SCL_OFF + 5]; if (c > OVFP_CAP) c = OVFP_CAP;
        const uint2* ovfp = (const uint2*)(ws + OVFP_OFF);
        for (uint32_t i = threadIdx.x; i < c; i += NTHR) {
            uint2 pr = ovfp[i];
            PROC(pr)
        }
    }
#undef PROC
    __syncthreads();   // drain: this block's atomics device-visible
    if (threadIdx.x == 0) {
        uint32_t old = atomicAdd(&ws[SCL_OFF + 10], 1u);
        amLast = (old == gridDim.x - 1u) ? 1 : 0;
    }
    __syncthreads();
    if (!amLast) return;
    // ---- last block: exact stable rank over the compact in-sub-bin set ----
    uint32_t c3 = atomicAdd(&ws[SCL_OFF + 9], 0u);
    if (c3 > CMP_CAP) c3 = CMP_CAP;
    for (uint32_t i = threadIdx.x; i < c3; i += NTHR) {
        uint2 pr;
        pr.x = atomicAdd(&cmp[2 * i], 0u);
        pr.y = atomicAdd(&cmp[2 * i + 1], 0u);
        l3s[i] = pr;
    }
    __syncthreads();
    for (uint32_t i = threadIdx.x; i < c3; i += NTHR) {
        uint2 me = l3s[i];
        uint32_t u = me.x & MASK31;
        uint32_t rank = 0;
        for (uint32_t p = 0; p < c3; ++p) {
            uint2 q2 = l3s[p];
            uint32_t up = q2.x & MASK31;
            rank += (up > u || (up == u && q2.y < me.y)) ? 1u : 0u;
        }
        if (rank < rem2) out[me.y] = me.x;
    }
}

extern "C" void kernel_launch(void* const* d_in, const int* in_sizes, int n_in,
                              void* d_out, int out_size, void* d_ws, size_t ws_size,
                              hipStream_t stream) {
    const uint32_t* x = (const uint32_t*)d_in[0];
    uint32_t* out = (uint32_t*)d_out;
    uint32_t* ws = (uint32_t*)d_ws;
    long long n = (long long)in_sizes[0];

    const double ratio = 0.5;  // SPARSE_COMPRESSION_RATIO
    long long k = (long long)((double)n * (1.0 - ratio));
    if (k < 1) k = 1;
    if (k > n) k = n;

    long long n4 = n >> 2;
    long long S = (n4 >> 5) << 2;            // sampled elements (1/32 of n)
    if (S < 4) S = (n4 << 2);
    long long ks = (long long)((double)k * ((double)S / (double)n));
    long long M = (long long)(9.0 * sqrt((double)S * 0.25)) + 64;  // ~9 sigma
    uint32_t ksmM = (uint32_t)((ks - M) < 1 ? 1 : (ks - M));
    uint32_t kspM = (uint32_t)((ks + M) > S ? S : (ks + M));

    zero_ws_kernel<<<(ZERO_WORDS + NTHR - 1) / NTHR, NTHR, 0, stream>>>(ws);
    sample_bracket_kernel<<<64, NTHR, 0, stream>>>((const v4u*)x, n4, ws, ksmM, kspM);
    fused_main_kernel<<<NBLK_MAIN, NTHR, 0, stream>>>(x, out, n, ws);
    cand_hist_sel_kernel<<<256, NTHR, 0, stream>>>(ws, (uint32_t)k);
    gather_fixup_kernel<<<256, NTHR, 0, stream>>>(ws, out);
}